// Round 7
// baseline (89.010 us; speedup 1.0000x reference)
//
#include <hip/hip_runtime.h>
#include <hip/hip_bf16.h>
#include <cstdint>
#include <cstddef>

#define TOKENS 16384
#define DMODEL 4096
#define NEXP   64
#define WINK   256                    // k-floats per window (1KB per row)
#define NWIN   (DMODEL / WINK)        // 16
#define NKC2   (DMODEL / 32)          // 128 K32-chunks total

typedef __attribute__((ext_vector_type(8))) short bf16x8;   // 8 bf16 = 4 VGPRs
typedef __attribute__((ext_vector_type(4))) float f32x4;    // 16x16 acc

// async global->LDS, 16B/lane; dest must be wave-uniform base + lane*16 (linear)
__device__ __forceinline__ void gld_lds16(const float* g, void* l) {
  __builtin_amdgcn_global_load_lds(
      (__attribute__((address_space(1))) const void*)g,
      (__attribute__((address_space(3))) void*)l, 16, 0, 0);
}

// 8 fp32 -> hi/lo bf16 (RNE hi, exact residual -> lo; ~2^-17 rel)
__device__ __forceinline__ void cvt_hilo8(const float f[8], bf16x8* hi, bf16x8* lo) {
  union { __hip_bfloat16 b; unsigned short u; } cv;
  bf16x8 hv, lv;
#pragma unroll
  for (int j = 0; j < 8; ++j) {
    __hip_bfloat16 hb = __float2bfloat16(f[j]);
    cv.b = hb; hv[j] = (short)cv.u;
    float r = f[j] - __bfloat162float(hb);
    cv.b = __float2bfloat16(r); lv[j] = (short)cv.u;
  }
  *hi = hv; *lo = lv;
}

// ---------------- kernel 1: W -> 16x16x32 B-fragments, bf16 hi/lo (as R5, verified) ----
// slot (kc2*4+eg)*64+l <- B[k=kc2*32+(l>>4)*8+j][e=eg*16+(l&15)] = W[e][k+j]
__global__ __launch_bounds__(256)
void prep_W(const float* __restrict__ W, uint4* __restrict__ wh, uint4* __restrict__ wl) {
  const int tid = blockIdx.x * 256 + threadIdx.x;   // 32768 threads
  const int l   = tid & 63;
  const int eg  = (tid >> 6) & 3;
  const int kc2 = tid >> 8;                          // 0..127
  const int e   = eg * 16 + (l & 15);
  const int k   = kc2 * 32 + (l >> 4) * 8;
  const float* src = W + (size_t)e * DMODEL + k;
  float f[8];
#pragma unroll
  for (int j = 0; j < 8; ++j) f[j] = src[j];
  bf16x8 hi, lo;
  cvt_hilo8(f, &hi, &lo);
  const int slot = (kc2 * 4 + eg) * 64 + l;
  wh[slot] = __builtin_bit_cast(uint4, hi);
  wl[slot] = __builtin_bit_cast(uint4, lo);
}

// ---------------- kernel 2: DMA-staged fused GEMM + bias + top-2 + softmax ----------------
// 512 blocks x 256 thr (2/CU). Block = 32 tokens; wave w = experts [w*16,+16), full K.
// x window (32 rows x 256 k fp32 = 32KB) DMA'd to LDS, double-buffered.
// Stored 16B-unit v of row r holds global unit v ^ (r&7)  (bank-uniform fragment reads).
__global__ __launch_bounds__(256, 2)
void gemm_topk(const float* __restrict__ x, const uint4* __restrict__ whB,
               const uint4* __restrict__ wlB, const float* __restrict__ b,
               float* __restrict__ out) {
  __shared__ __align__(16) char lds[65536];   // [buf0 32K][buf1 32K]
  const int tid = threadIdx.x;
  const int l   = tid & 63;
  const int w   = tid >> 6;
  const int t0  = blockIdx.x * 32;

  char* xb0 = lds;
  char* xb1 = lds + 32768;
  const uint4* whp = whB + w * 64 + l;   // stride 256 uint4 per kc2
  const uint4* wlp = wlB + w * 64 + l;

  // stage window win into buf: round p stages rows p*4+{0..3}; wave w -> row p*4+w,
  // one 1KB-contiguous (lane-permuted) run per instruction.
  auto stage = [&](int win, char* buf) {
#pragma unroll
    for (int p = 0; p < 8; ++p) {
      const int r  = p * 4 + w;
      const int sb = (l * 16) ^ ((r & 7) << 4);          // swizzled source byte
      const float* src = x + (size_t)(t0 + r) * DMODEL + win * WINK + (sb >> 2);
      gld_lds16(src, buf + p * 4096 + tid * 16);
    }
  };

  f32x4 acc0 = {0.f, 0.f, 0.f, 0.f}, acc1 = {0.f, 0.f, 0.f, 0.f};
  uint4 ph[2], pl[2];

  auto compute = [&](const char* buf, int wi) {
#pragma unroll
    for (int c = 0; c < 8; ++c) {
      uint4 bhu = ph[c & 1], blu = pl[c & 1];
      const int kci = wi * 8 + c;
      if (kci + 2 < NKC2) {                              // depth-2 L2 rotation
        ph[c & 1] = whp[(size_t)(kci + 2) * 256];
        pl[c & 1] = wlp[(size_t)(kci + 2) * 256];
      }
      const int r0 = l & 15, r1 = 16 + (l & 15);
      const int ku = c * 8 + (l >> 4) * 2;               // first 16B-unit index
      const int s0 = r0 & 7;                             // == r1 & 7
      float4 f00 = *(const float4*)(buf + r0 * 1024 + ((ku ^ s0) << 4));
      float4 f01 = *(const float4*)(buf + r0 * 1024 + (((ku + 1) ^ s0) << 4));
      float4 f10 = *(const float4*)(buf + r1 * 1024 + ((ku ^ s0) << 4));
      float4 f11 = *(const float4*)(buf + r1 * 1024 + (((ku + 1) ^ s0) << 4));
      float t0f[8] = {f00.x, f00.y, f00.z, f00.w, f01.x, f01.y, f01.z, f01.w};
      float t1f[8] = {f10.x, f10.y, f10.z, f10.w, f11.x, f11.y, f11.z, f11.w};
      bf16x8 ah0, al0, ah1, al1;
      cvt_hilo8(t0f, &ah0, &al0);
      cvt_hilo8(t1f, &ah1, &al1);
      bf16x8 bh = __builtin_bit_cast(bf16x8, bhu);
      bf16x8 bl = __builtin_bit_cast(bf16x8, blu);
      // fp32-emulated: hi*hi + hi*lo + lo*hi
      acc0 = __builtin_amdgcn_mfma_f32_16x16x32_bf16(ah0, bh, acc0, 0, 0, 0);
      acc1 = __builtin_amdgcn_mfma_f32_16x16x32_bf16(ah1, bh, acc1, 0, 0, 0);
      acc0 = __builtin_amdgcn_mfma_f32_16x16x32_bf16(ah0, bl, acc0, 0, 0, 0);
      acc1 = __builtin_amdgcn_mfma_f32_16x16x32_bf16(ah1, bl, acc1, 0, 0, 0);
      acc0 = __builtin_amdgcn_mfma_f32_16x16x32_bf16(al0, bh, acc0, 0, 0, 0);
      acc1 = __builtin_amdgcn_mfma_f32_16x16x32_bf16(al1, bh, acc1, 0, 0, 0);
    }
  };

  // prologue
  stage(0, xb0);
  ph[0] = whp[0];   pl[0] = wlp[0];
  ph[1] = whp[256]; pl[1] = wlp[256];
  __syncthreads();                    // drains win0 DMA (vmcnt) for all waves
  stage(1, xb1);                      // win1 in flight under compute(win0)

  for (int wi = 0; wi < NWIN; wi += 2) {
    compute(xb0, wi);
    __syncthreads();                  // drains win(wi+1); xb0 free
    if (wi + 2 < NWIN) stage(wi + 2, xb0);
    compute(xb1, wi + 1);
    __syncthreads();                  // drains win(wi+2); xb1 free
    if (wi + 3 < NWIN) stage(wi + 3, xb1);
  }

  // logits -> LDS (alias xb0; safe: loop ended with barrier), + bias
  // C/D 16x16x32 (verified): col=lane&15 (expert), row=(lane>>4)*4+reg (token)
  float* red = (float*)lds;           // [32][66]
  const float bias = b[w * 16 + (l & 15)];
#pragma unroll
  for (int reg = 0; reg < 4; ++reg) {
    const int tr = (l >> 4) * 4 + reg;
    red[tr * 66 + w * 16 + (l & 15)]        = acc0[reg] + bias;
    red[(16 + tr) * 66 + w * 16 + (l & 15)] = acc1[reg] + bias;
  }
  __syncthreads();

  // top-2 + softmax: wave w handles tokens w*8..w*8+7, lane = expert
#pragma unroll
  for (int i = 0; i < 8; ++i) {
    const int tl = w * 8 + i;
    const float v = red[tl * 66 + l];

    float m1 = v; int i1 = l;
#pragma unroll
    for (int off = 32; off > 0; off >>= 1) {
      float ov = __shfl_xor(m1, off, 64);
      int   oi = __shfl_xor(i1, off, 64);
      if (ov > m1 || (ov == m1 && oi < i1)) { m1 = ov; i1 = oi; }
    }
    float v2 = (l == i1) ? -__builtin_inff() : v;
    float m2 = v2; int i2 = l;
#pragma unroll
    for (int off = 32; off > 0; off >>= 1) {
      float ov = __shfl_xor(m2, off, 64);
      int   oi = __shfl_xor(i2, off, 64);
      if (ov > m2 || (ov == m2 && oi < i2)) { m2 = ov; i2 = oi; }
    }
    float e = __expf(v - m1);
#pragma unroll
    for (int off = 32; off > 0; off >>= 1) e += __shfl_xor(e, off, 64);

    if (l == 0) {
      const int t = t0 + tl;
      out[(size_t)t * 2 + 0] = (float)i1;
      out[(size_t)t * 2 + 1] = (float)i2;
      float inv = 1.0f / e;
      out[(size_t)TOKENS * 2 + (size_t)t * 2 + 0] = inv;
      out[(size_t)TOKENS * 2 + (size_t)t * 2 + 1] = __expf(m2 - m1) * inv;
    }
  }
}

extern "C" void kernel_launch(void* const* d_in, const int* in_sizes, int n_in,
                              void* d_out, int out_size, void* d_ws, size_t ws_size,
                              hipStream_t stream) {
  const float* x = (const float*)d_in[0];
  const float* W = (const float*)d_in[1];
  const float* b = (const float*)d_in[2];
  float* out = (float*)d_out;

  uint4* wh = (uint4*)d_ws;          // 32768 slots * 16B = 512 KB
  uint4* wl = wh + 32768;            // 512 KB

  hipLaunchKernelGGL(prep_W,    dim3(128),         dim3(256), 0, stream, W, wh, wl);
  hipLaunchKernelGGL(gemm_topk, dim3(TOKENS / 32), dim3(256), 0, stream, x, wh, wl, b, out);
}

// Round 8
// 85.096 us; speedup vs baseline: 1.0460x; 1.0460x over previous
//
#include <hip/hip_runtime.h>
#include <hip/hip_bf16.h>
#include <cstdint>
#include <cstddef>

#define TOKENS 16384
#define DMODEL 4096
#define NEXP   64
#define NWAVE  4
#define WINK   256                    // k-floats per window (1KB per row)
#define NWIN   (DMODEL / WINK)        // 16 windows
#define WCH    (WINK / 16)            // 16 k16-chunks per window
#define CPW    (WCH / NWAVE)          // 4 chunks per wave per window

typedef __attribute__((ext_vector_type(8)))  short bf16x8;   // 8 bf16 = 4 VGPRs
typedef __attribute__((ext_vector_type(16))) float f32x16;   // 32x32 acc

// async global->LDS, 16B/lane; dest = wave-uniform base + lane*16 (linear)
__device__ __forceinline__ void gld_lds16(const float* g, void* l) {
  __builtin_amdgcn_global_load_lds(
      (__attribute__((address_space(1))) const void*)g,
      (__attribute__((address_space(3))) void*)l, 16, 0, 0);
}

// 8 fp32 -> hi/lo bf16 (RNE hi, exact residual -> lo; ~2^-17 rel)
__device__ __forceinline__ void cvt_hilo8(const float f[8], bf16x8* hi, bf16x8* lo) {
  union { __hip_bfloat16 b; unsigned short u; } cv;
  bf16x8 hv, lv;
#pragma unroll
  for (int j = 0; j < 8; ++j) {
    __hip_bfloat16 hb = __float2bfloat16(f[j]);
    cv.b = hb; hv[j] = (short)cv.u;
    float r = f[j] - __bfloat162float(hb);
    cv.b = __float2bfloat16(r); lv[j] = (short)cv.u;
  }
  *hi = hv; *lo = lv;
}

// ---------------- kernel 1: W -> 32x32x16 B-fragments, bf16 hi/lo (R2-R4, verified) ----
// slot (kc*2+et)*64+l <- B[k=kc*16+(l>>5)*8+j][e=et*32+(l&31)] = W[e][k+j]
__global__ __launch_bounds__(256)
void prep_W(const float* __restrict__ W, uint4* __restrict__ wh, uint4* __restrict__ wl) {
  const int tid = blockIdx.x * 256 + threadIdx.x;   // 32768 threads
  const int l  = tid & 63;
  const int et = (tid >> 6) & 1;
  const int kc = tid >> 7;                           // 0..255 (global k16-chunk)
  const int e  = et * 32 + (l & 31);
  const int k  = kc * 16 + (l >> 5) * 8;
  const float* src = W + (size_t)e * DMODEL + k;
  float f[8];
#pragma unroll
  for (int j = 0; j < 8; ++j) f[j] = src[j];
  bf16x8 hi, lo;
  cvt_hilo8(f, &hi, &lo);
  const int slot = (kc * 2 + et) * 64 + l;
  wh[slot] = __builtin_bit_cast(uint4, hi);
  wl[slot] = __builtin_bit_cast(uint4, lo);
}

// ---------------- kernel 2: DMA-staged GEMM, waves split K, fused epilogue ----------------
// 512 blocks x 256 thr (2/CU). Block = 32 tokens x 64 experts. Window = 32 rows x 1KB,
// DMA'd in 32 x 1KB-contiguous requests (queue-slot-efficient), double-buffered.
// Stored 16B-unit s of row r holds global unit s ^ (r&7); reads apply the same XOR.
__global__ __launch_bounds__(256, 2)
void gemm_topk(const float* __restrict__ x, const uint4* __restrict__ whB,
               const uint4* __restrict__ wlB, const float* __restrict__ b,
               float* __restrict__ out) {
  __shared__ __align__(16) char lds[65536];   // [xb0 32K][xb1 32K]
  const int tid = threadIdx.x;
  const int l   = tid & 63;
  const int w   = tid >> 6;
  const int t0  = blockIdx.x * 32;
  const int row = l & 31, g = l >> 5;

  char* xb0 = lds;
  char* xb1 = lds + 32768;
  const uint4* whp = whB + l;
  const uint4* wlp = wlB + l;

  // stage window win: wave w instr p -> row p*4+w, one 1KB contiguous run (lane-permuted)
  auto stage = [&](int win, char* buf) {
#pragma unroll
    for (int p = 0; p < 8; ++p) {
      const int r  = p * 4 + w;
      const int sb = (l * 16) ^ ((r & 7) << 4);          // swizzled source byte in [0,1024)
      const float* src = x + (size_t)(t0 + r) * DMODEL + win * WINK + (sb >> 2);
      gld_lds16(src, buf + p * 4096 + tid * 16);
    }
  };

  f32x16 acc0, acc1;
#pragma unroll
  for (int i = 0; i < 16; ++i) { acc0[i] = 0.f; acc1[i] = 0.f; }

  // compute: wave w consumes window chunks [w*4, w*4+4); cvt once per element per block
  auto compute = [&](const char* buf, int win) {
    uint4 bh0[4], bh1[4], bl0[4], bl1[4];
#pragma unroll
    for (int c = 0; c < 4; ++c) {                        // W for my 4 chunks, all in flight
      const size_t base = (size_t)(win * WCH + w * CPW + c) * 128;
      bh0[c] = whp[base];      bh1[c] = whp[base + 64];
      bl0[c] = wlp[base];      bl1[c] = wlp[base + 64];
    }
#pragma unroll
    for (int c = 0; c < 4; ++c) {
      const int u = (w * CPW + c) * 4 + g * 2;           // window-local 16B-unit
      const int sw = (row & 7);
      float4 a0 = *(const float4*)(buf + row * 1024 + ((u ^ sw) << 4));
      float4 a1 = *(const float4*)(buf + row * 1024 + (((u + 1) ^ sw) << 4));
      float f[8] = {a0.x, a0.y, a0.z, a0.w, a1.x, a1.y, a1.z, a1.w};
      bf16x8 ah, al;
      cvt_hilo8(f, &ah, &al);
      bf16x8 vh0 = __builtin_bit_cast(bf16x8, bh0[c]);
      bf16x8 vh1 = __builtin_bit_cast(bf16x8, bh1[c]);
      bf16x8 vl0 = __builtin_bit_cast(bf16x8, bl0[c]);
      bf16x8 vl1 = __builtin_bit_cast(bf16x8, bl1[c]);
      // fp32-emulated: hi*hi + hi*lo + lo*hi
      acc0 = __builtin_amdgcn_mfma_f32_32x32x16_bf16(ah, vh0, acc0, 0, 0, 0);
      acc1 = __builtin_amdgcn_mfma_f32_32x32x16_bf16(ah, vh1, acc1, 0, 0, 0);
      acc0 = __builtin_amdgcn_mfma_f32_32x32x16_bf16(ah, vl0, acc0, 0, 0, 0);
      acc1 = __builtin_amdgcn_mfma_f32_32x32x16_bf16(ah, vl1, acc1, 0, 0, 0);
      acc0 = __builtin_amdgcn_mfma_f32_32x32x16_bf16(al, vh0, acc0, 0, 0, 0);
      acc1 = __builtin_amdgcn_mfma_f32_32x32x16_bf16(al, vh1, acc1, 0, 0, 0);
    }
  };

  // prologue
  stage(0, xb0);
  stage(1, xb1);
  __syncthreads();                    // drains DMA (vmcnt) for all waves

  for (int wi = 0; wi < NWIN; wi += 2) {
    compute(xb0, wi);
    __syncthreads();                  // xb0 readers done; win(wi+1) DMA also drained
    if (wi + 2 < NWIN) stage(wi + 2, xb0);
    compute(xb1, wi + 1);
    __syncthreads();                  // xb1 readers done; win(wi+2) DMA drained
    if (wi + 3 < NWIN) stage(wi + 3, xb1);
  }

  // ---- epilogue (verbatim R4, verified): K-split reduce + bias + top-2 + softmax ----
  // C/D 32x32 layout: expert col = lane&31, token row rr = (r&3)+8*(r>>2)+4*(lane>>5)
  float* red = (float*)lds;           // [4][32*64] = 32KB, aliases xb0 (safe: post-barrier)
  {
    float* rp = red + w * (32 * NEXP);
#pragma unroll
    for (int r = 0; r < 16; ++r) {
      const int rr = (r & 3) + 8 * (r >> 2) + 4 * g;
      rp[rr * NEXP + row]      = acc0[r];
      rp[rr * NEXP + 32 + row] = acc1[r];
    }
  }
  __syncthreads();

  const float bias = b[tid & 63];
#pragma unroll
  for (int j = 0; j < 8; ++j) {
    const int f = tid + 256 * j;      // bank = tid%32, conflict-free; expert = tid&63
    float s = red[f] + red[2048 + f] + red[4096 + f] + red[6144 + f] + bias;
    red[f] = s;                       // owner-exclusive
  }
  __syncthreads();

#pragma unroll
  for (int i = 0; i < 8; ++i) {
    const int tl = w * 8 + i;
    const float v = red[tl * NEXP + l];

    float m1 = v; int i1 = l;
#pragma unroll
    for (int off = 32; off > 0; off >>= 1) {
      float ov = __shfl_xor(m1, off, 64);
      int   oi = __shfl_xor(i1, off, 64);
      if (ov > m1 || (ov == m1 && oi < i1)) { m1 = ov; i1 = oi; }
    }
    float v2 = (l == i1) ? -__builtin_inff() : v;
    float m2 = v2; int i2 = l;
#pragma unroll
    for (int off = 32; off > 0; off >>= 1) {
      float ov = __shfl_xor(m2, off, 64);
      int   oi = __shfl_xor(i2, off, 64);
      if (ov > m2 || (ov == m2 && oi < i2)) { m2 = ov; i2 = oi; }
    }
    float e = __expf(v - m1);
#pragma unroll
    for (int off = 32; off > 0; off >>= 1) e += __shfl_xor(e, off, 64);

    if (l == 0) {
      const int t = t0 + tl;
      out[(size_t)t * 2 + 0] = (float)i1;
      out[(size_t)t * 2 + 1] = (float)i2;
      float inv = 1.0f / e;
      out[(size_t)TOKENS * 2 + (size_t)t * 2 + 0] = inv;
      out[(size_t)TOKENS * 2 + (size_t)t * 2 + 1] = __expf(m2 - m1) * inv;
    }
  }
}

extern "C" void kernel_launch(void* const* d_in, const int* in_sizes, int n_in,
                              void* d_out, int out_size, void* d_ws, size_t ws_size,
                              hipStream_t stream) {
  const float* x = (const float*)d_in[0];
  const float* W = (const float*)d_in[1];
  const float* b = (const float*)d_in[2];
  float* out = (float*)d_out;

  uint4* wh = (uint4*)d_ws;          // 32768 slots * 16B = 512 KB
  uint4* wl = wh + 32768;            // 512 KB

  hipLaunchKernelGGL(prep_W,    dim3(128),         dim3(256), 0, stream, W, wh, wl);
  hipLaunchKernelGGL(gemm_topk, dim3(TOKENS / 32), dim3(256), 0, stream, x, wh, wl, b, out);
}